// Round 6
// baseline (452.321 us; speedup 1.0000x reference)
//
#include <hip/hip_runtime.h>

// B=4, C=64, H=W=64, N=4096, GROUPS=32 (2 ch/group), R=4.
// ws layout (bytes):
#define STATS_OFF 0                       // [1024][5] fp32 partial sums (bc*4+chunk)
#define AD_OFF    20480                   // [src(3)][b*64+c][2] fp32 (a, d)
#define SEY_OFF   26624                   // [b*64+c] fp32
#define BIAS_OFF  27648                   // fp32[1280]: [0:256) v(b,o); [256:768) q(bh,o); [768:1280) k(bh,o)
#define WQB_OFF   32768                   // bf16 wq*qscale [o][c] 8KB
#define WKB_OFF   40960                   // bf16 wk
#define WVB_OFF   49152                   // bf16 wv
#define Q_OFF     57344                   // [bh][n][c] bf16, 4MB (q pre-scaled)
#define K_OFF     (Q_OFF + 4194304)       // [bh][n][c] bf16, 4MB
#define V_OFF     (K_OFF + 4194304)       // [b][c][n]  bf16, 2MB
#define PO_OFF    (V_OFF + 2097152)       // [bh][js][n][c] bf16 partials, then pl fp32

#define QSCALE 0.18033688f                // 0.125 * log2(e)

typedef __attribute__((ext_vector_type(8))) short  short8;
typedef __attribute__((ext_vector_type(4))) short  s16x4;
typedef __attribute__((ext_vector_type(2))) unsigned int u32x2;
typedef __attribute__((ext_vector_type(4))) float  f32x4;

#if __has_builtin(__builtin_amdgcn_mfma_f32_16x16x16bf16_1k)
#define HAS_1K 1
#else
#define HAS_1K 0
#endif

#if __has_builtin(__builtin_amdgcn_exp2f)
__device__ inline float fexp2(float x) { return __builtin_amdgcn_exp2f(x); }  // raw v_exp_f32
#else
__device__ inline float fexp2(float x) { return exp2f(x); }
#endif

__device__ inline ushort f2b(float f) {   // round-half-up to bf16
  return (ushort)((__float_as_uint(f) + 0x8000u) >> 16);
}
__device__ inline unsigned pack2(float x, float y) {  // two bf16 in one dword
  unsigned ux = __float_as_uint(x) + 0x8000u;
  unsigned uy = __float_as_uint(y) + 0x8000u;
  return __builtin_amdgcn_perm(uy, ux, 0x07060302);
}
__device__ inline float b2f(ushort u) { return __uint_as_float(((unsigned)u) << 16); }

__device__ inline f32x4 mfma16(short8 a, short8 b, f32x4 c) {
  return __builtin_amdgcn_mfma_f32_16x16x32_bf16(a, b, c, 0, 0, 0);
}

__device__ inline float wsum64(float v) {
  #pragma unroll
  for (int o = 32; o > 0; o >>= 1) v += __shfl_down(v, o, 64);
  return v;
}

// ---------------- kernel 1: per-(b,c) partial sums, 4 spatial chunks -----------------
__global__ __launch_bounds__(256) void sc_stats(const float* __restrict__ x1,
                                                const float* __restrict__ x2,
                                                float* __restrict__ stats) {
  int blk = blockIdx.x;                 // 1024 = bc*4 + chunk
  int bc = blk >> 2, chunk = blk & 3;
  const float4* p1 = (const float4*)(x1 + (size_t)bc * 4096 + chunk * 1024);
  const float4* p2 = (const float4*)(x2 + (size_t)bc * 4096 + chunk * 1024);
  float4 a = p1[threadIdx.x], b = p2[threadIdx.x];
  float s1 = a.x + a.y + a.z + a.w;
  float q1 = a.x*a.x + a.y*a.y + a.z*a.z + a.w*a.w;
  float s2 = b.x + b.y + b.z + b.w;
  float q2 = b.x*b.x + b.y*b.y + b.z*b.z + b.w*b.w;
  float p12 = a.x*b.x + a.y*b.y + a.z*b.z + a.w*b.w;
  s1 = wsum64(s1); q1 = wsum64(q1); s2 = wsum64(s2); q2 = wsum64(q2); p12 = wsum64(p12);
  __shared__ float red[4][5];
  int w = threadIdx.x >> 6, ln = threadIdx.x & 63;
  if (ln == 0) { red[w][0] = s1; red[w][1] = q1; red[w][2] = s2; red[w][3] = q2; red[w][4] = p12; }
  __syncthreads();
  if (threadIdx.x < 5) {
    float acc = 0;
    #pragma unroll
    for (int ww = 0; ww < 4; ww++) acc += red[ww][threadIdx.x];
    stats[(size_t)blk * 5 + threadIdx.x] = acc;
  }
}

// ------------- kernel 2: SE MLP + GN fold + folded biases + bf16 weights -------------
__global__ __launch_bounds__(256) void sc_prep(const float* __restrict__ stats,
                                               const float* __restrict__ w1,
                                               const float* __restrict__ w2,
                                               const float* __restrict__ gamma,
                                               const float* __restrict__ beta,
                                               const float* __restrict__ wq, const float* __restrict__ bq,
                                               const float* __restrict__ wk, const float* __restrict__ bk,
                                               const float* __restrict__ wv, const float* __restrict__ bv,
                                               float* __restrict__ ad, float* __restrict__ sey,
                                               float* __restrict__ biasbuf,
                                               ushort* __restrict__ wqb, ushort* __restrict__ wkb,
                                               ushort* __restrict__ wvb) {
  int t = threadIdx.x; int b = t >> 6, c = t & 63;
  float s1 = 0, q1 = 0, s2 = 0, q2 = 0, p12 = 0;
  #pragma unroll
  for (int ch = 0; ch < 4; ch++) {
    const float* sp = stats + (size_t)(t * 4 + ch) * 5;
    s1 += sp[0]; q1 += sp[1]; s2 += sp[2]; q2 += sp[3]; p12 += sp[4];
  }
  float sx = s1 + s2, qx = q1 + q2 + 2.f * p12;
  __shared__ float smu[256], sS[3][256], sQ[3][256], sy[16], sdd[3][256];
  smu[t] = sx * (1.f / 4096.f);
  sS[0][t] = sx; sQ[0][t] = qx; sS[1][t] = s1; sQ[1][t] = q1; sS[2][t] = s2; sQ[2][t] = q2;
  __syncthreads();
  if (t < 16) {
    int bb = t >> 2, r = t & 3; float acc = 0.f;
    for (int cc = 0; cc < 64; cc++) acc += w1[r*64+cc] * smu[bb*64+cc];
    sy[t] = fmaxf(acc, 0.f);
  }
  __syncthreads();
  float acc = 0.f;
  #pragma unroll
  for (int r = 0; r < 4; r++) acc += w2[c*4+r] * sy[b*4+r];
  sey[t] = 1.f / (1.f + fexp2(-acc * 1.44269504f));
  int prt = t ^ 1;
  float g = gamma[c], bt = beta[c];
  #pragma unroll
  for (int s = 0; s < 3; s++) {
    float S = sS[s][t] + sS[s][prt], Q = sQ[s][t] + sQ[s][prt];
    float mean = S * (1.f / 8192.f);
    float var  = Q * (1.f / 8192.f) - mean * mean;
    float rstd = rsqrtf(var + 1e-6f);
    float a = g * rstd;
    float d = bt - mean * a;
    ad[((s*256) + t)*2 + 0] = a;
    ad[((s*256) + t)*2 + 1] = d;
    sdd[s][t] = d;
  }
  __syncthreads();
  // folded biases: bias' = W*d + bias (q scaled); 1280 of them
  #pragma unroll
  for (int k = 0; k < 5; k++) {
    int idx = k * 256 + t;
    const float* W; const float* bs; const float* dd; int o; float scale = 1.f;
    if (idx < 256)      { int bb = idx >> 6; o = idx & 63; W = wv; bs = bv; dd = &sdd[0][bb*64]; }
    else if (idx < 768) { int r = idx - 256; int bh = r >> 6; o = r & 63; W = wq; bs = bq;
                          dd = &sdd[1 + (bh & 1)][(bh >> 1)*64]; scale = QSCALE; }
    else                { int r = idx - 768; int bh = r >> 6; o = r & 63; W = wk; bs = bk;
                          dd = &sdd[1 + (bh & 1)][(bh >> 1)*64]; }
    float a2 = bs[o];
    for (int cc = 0; cc < 64; cc++) a2 += W[o*64+cc] * dd[cc];
    biasbuf[idx] = a2 * scale;
  }
  for (int i = t; i < 4096; i += 256) {
    wqb[i] = f2b(wq[i] * QSCALE);
    wkb[i] = f2b(wk[i]);
    wvb[i] = f2b(wv[i]);
  }
}

// ------------- kernel 3: GN + 1x1 conv projections via MFMA, LDS-staged stores -------------
__global__ __launch_bounds__(256) void sc_proj(const float* __restrict__ x1, const float* __restrict__ x2,
    const float* __restrict__ ad, const float* __restrict__ biasbuf,
    const ushort* __restrict__ wqb, const ushort* __restrict__ wkb, const ushort* __restrict__ wvb,
    ushort* __restrict__ qout, ushort* __restrict__ kout, ushort* __restrict__ vout) {
  int pt = blockIdx.x, src = blockIdx.y, b = blockIdx.z, t = threadIdx.x;
  __shared__ ushort xlds[64 * 66];   // xn tile [p][c], bf16
  __shared__ ushort olds[64 * 66];   // output assembly tile
  __shared__ float sbias[2][64];
  if (t < 128) {
    int proj = t >> 6, o = t & 63;
    float bb;
    if (src == 0) bb = (proj == 0) ? biasbuf[b*64 + o] : 0.f;
    else          bb = biasbuf[256 + (proj ? 512 : 0) + (b*2 + src - 1)*64 + o];
    sbias[proj][o] = bb;
  }
  {
    int c = t >> 2, pq = (t & 3) * 16;
    const float* px1 = x1 + ((size_t)(b*64 + c))*4096 + pt*64 + pq;
    const float* px2 = x2 + ((size_t)(b*64 + c))*4096 + pt*64 + pq;
    float av = ad[((src*256) + b*64 + c)*2 + 0];
    #pragma unroll
    for (int k4 = 0; k4 < 4; k4++) {
      float4 v1 = *(const float4*)(px1 + 4*k4);
      float xv[4];
      if (src == 1) { xv[0]=v1.x; xv[1]=v1.y; xv[2]=v1.z; xv[3]=v1.w; }
      else {
        float4 v2 = *(const float4*)(px2 + 4*k4);
        if (src == 2) { xv[0]=v2.x; xv[1]=v2.y; xv[2]=v2.z; xv[3]=v2.w; }
        else { xv[0]=v1.x+v2.x; xv[1]=v1.y+v2.y; xv[2]=v1.z+v2.z; xv[3]=v1.w+v2.w; }
      }
      #pragma unroll
      for (int k = 0; k < 4; k++)
        xlds[(pq + 4*k4 + k)*66 + c] = f2b(av * xv[k]);
    }
  }
  __syncthreads();
  int wave = t >> 6, lane = t & 63, quad = lane >> 4, l15 = lane & 15;
  int orow = t >> 2, ocol = (t & 3) * 16;   // coalesced write-out mapping
  if (src == 0) {
    // V[o][p]: A = Wv (m=o,k=c), B = xn (k=c,n=p). wave = o-sub.
    const ushort* ap = wvb + (wave*16 + l15)*64 + quad*8;
    short8 a0 = *(const short8*)ap;
    short8 a1 = *(const short8*)(ap + 32);
    f32x4 cinit;
    #pragma unroll
    for (int r = 0; r < 4; r++) cinit[r] = sbias[0][wave*16 + quad*4 + r];
    #pragma unroll
    for (int s = 0; s < 4; s++) {
      const ushort* bp = xlds + (s*16 + l15)*66 + quad*8;
      short8 b0 = *(const short8*)bp;
      short8 b1 = *(const short8*)(bp + 32);
      f32x4 acc = mfma16(a0, b0, cinit);
      acc = mfma16(a1, b1, acc);
      #pragma unroll
      for (int r = 0; r < 4; r++)
        olds[(wave*16 + quad*4 + r)*66 + s*16 + l15] = f2b(acc[r]);   // [o][p]
    }
    __syncthreads();
    uint4 w0 = *(const uint4*)&olds[orow*66 + ocol];
    uint4 w1 = *(const uint4*)&olds[orow*66 + ocol + 8];
    ushort* dst = vout + ((size_t)(b*64 + orow))*4096 + pt*64 + ocol;
    *(uint4*)dst = w0; *(uint4*)(dst + 8) = w1;
  } else {
    // Q/K[p][o]: A = xn (m=p,k=c), B = W (k=c,n=o). wave = p-sub.
    int bh = b*2 + (src - 1);
    const ushort* ap = xlds + (wave*16 + l15)*66 + quad*8;
    short8 a0 = *(const short8*)ap;
    short8 a1 = *(const short8*)(ap + 32);
    #pragma unroll
    for (int proj = 0; proj < 2; proj++) {
      const ushort* Wb = proj == 0 ? wqb : wkb;
      ushort* dst = proj == 0 ? qout : kout;
      #pragma unroll
      for (int s = 0; s < 4; s++) {
        const ushort* bp = Wb + (s*16 + l15)*64 + quad*8;
        short8 b0 = *(const short8*)bp;
        short8 b1 = *(const short8*)(bp + 32);
        float bb = sbias[proj][s*16 + l15];
        f32x4 acc = {bb, bb, bb, bb};
        acc = mfma16(a0, b0, acc);
        acc = mfma16(a1, b1, acc);
        #pragma unroll
        for (int r = 0; r < 4; r++)
          olds[(wave*16 + quad*4 + r)*66 + s*16 + l15] = f2b(acc[r]);  // [p][o]
      }
      __syncthreads();
      uint4 w0 = *(const uint4*)&olds[orow*66 + ocol];
      uint4 w1 = *(const uint4*)&olds[orow*66 + ocol + 8];
      ushort* dp = dst + ((size_t)bh*4096 + pt*64 + orow)*64 + ocol;
      *(uint4*)dp = w0; *(uint4*)(dp + 8) = w1;
      if (proj == 0) __syncthreads();   // olds reused by proj 1
    }
  }
}

// ------------- kernel 4: flash attention, S^T + _1k, K/V in LDS, reg prefetch -------------
// grid 8*32*njs: bh = blk&7 (XCD-local K/V), rest = blk>>3: js = rest&(njs-1), itile = rest>>jsbits.
__global__ __launch_bounds__(256, 8) void sc_flash(const ushort* __restrict__ qg,
                                                   const ushort* __restrict__ kg,
                                                   const ushort* __restrict__ vg,
                                                   ushort* __restrict__ po,
                                                   float* __restrict__ pl,
                                                   int jsbits) {
  int blk = blockIdx.x;
  int bh = blk & 7, rest = blk >> 3;
  int njs = 1 << jsbits, njt = 64 >> jsbits;
  int js = rest & (njs - 1), itile = rest >> jsbits;
  int jbase = js * (njt << 6);
  int b = bh >> 1;
  int t = threadIdx.x, wave = t >> 6, lane = t & 63, quad = lane >> 4, l15 = lane & 15;
  int i0 = itile * 128 + wave * 32;

  __shared__ ushort Klds[64 * 72];       // [j][c]
  __shared__ ushort Vlds[64 * 72];       // [c][j]
#if !HAS_1K
  __shared__ ushort Plds[4][32 * 72];    // per-wave P [i][j] (fallback only)
#endif

  // Q B-frags (B[k=c][n=i]): lane -> i=l15, c=quad*8(+32); two i-blocks
  const ushort* qbase = qg + ((size_t)bh * 4096 + i0 + l15) * 64 + quad * 8;
  short8 Qb[2][2];
  Qb[0][0] = *(const short8*)qbase;
  Qb[0][1] = *(const short8*)(qbase + 32);
  Qb[1][0] = *(const short8*)(qbase + 16 * 64);
  Qb[1][1] = *(const short8*)(qbase + 16 * 64 + 32);

  f32x4 O[2][4]; const f32x4 zero4 = {0.f, 0.f, 0.f, 0.f};
  #pragma unroll
  for (int ib = 0; ib < 2; ib++)
    #pragma unroll
    for (int cb = 0; cb < 4; cb++) O[ib][cb] = zero4;
  float lsum[2] = {0.f, 0.f};

  // staging: thread -> row t>>2 (j for K, c for V), 32B chunk (t&3)*16
  int sr = t >> 2, sc = (t & 3) * 16;
  const ushort* ksrc = kg + ((size_t)bh * 4096 + jbase + sr) * 64 + sc;
  const ushort* vsrc = vg + ((size_t)(b * 64 + sr)) * 4096 + jbase + sc;
  ushort* kdst = Klds + sr * 72 + sc;
  ushort* vdst = Vlds + sr * 72 + sc;

  // register prefetch of tile 0
  uint4 kr0 = *(const uint4*)ksrc, kr1 = *(const uint4*)(ksrc + 8);
  uint4 vr0 = *(const uint4*)vsrc, vr1 = *(const uint4*)(vsrc + 8);
  ksrc += 4096; vsrc += 64;

  #pragma unroll 1
  for (int jt = 0; jt < njt; jt++) {
    __syncthreads();                     // prior iteration's LDS reads done
    *(uint4*)kdst = kr0; *(uint4*)(kdst + 8) = kr1;
    *(uint4*)vdst = vr0; *(uint4*)(vdst + 8) = vr1;
    __syncthreads();
    if (jt + 1 < njt) {                  // issue next tile's loads; land during compute
      kr0 = *(const uint4*)ksrc; kr1 = *(const uint4*)(ksrc + 8);
      vr0 = *(const uint4*)vsrc; vr1 = *(const uint4*)(vsrc + 8);
      ksrc += 4096; vsrc += 64;
    }

    // S^T = K Q^T : D[j=16s+quad*4+r][i=ib*16+l15]
    f32x4 S[2][4];
    #pragma unroll
    for (int s = 0; s < 4; s++) {
      const ushort* kp = Klds + (s * 16 + l15) * 72 + quad * 8;
      short8 ka0 = *(const short8*)kp;
      short8 ka1 = *(const short8*)(kp + 32);
      #pragma unroll
      for (int ib = 0; ib < 2; ib++) {
        f32x4 acc = mfma16(ka0, Qb[ib][0], zero4);
        S[ib][s] = mfma16(ka1, Qb[ib][1], acc);
      }
    }

    // P = exp2(S) (no-max softmax; scores bounded); per-lane l accumulation
#if HAS_1K
    s16x4 Pb[2][4];
#endif
    #pragma unroll
    for (int ib = 0; ib < 2; ib++) {
      #pragma unroll
      for (int s = 0; s < 4; s++) {
        float p0 = fexp2(S[ib][s][0]);
        float p1 = fexp2(S[ib][s][1]);
        float p2 = fexp2(S[ib][s][2]);
        float p3 = fexp2(S[ib][s][3]);
        lsum[ib] += (p0 + p1) + (p2 + p3);
#if HAS_1K
        u32x2 wpk = {pack2(p0, p1), pack2(p2, p3)};
        Pb[ib][s] = __builtin_bit_cast(s16x4, wpk);
#else
        ushort* pw = &Plds[wave][(ib * 16 + l15) * 72 + s * 16 + quad * 4];
        pw[0] = f2b(p0); pw[1] = f2b(p1); pw[2] = f2b(p2); pw[3] = f2b(p3);
#endif
      }
    }

#if HAS_1K
    // O += P V : 16x16x16_1k, A = P (S^T C-layout direct), B = V b64 frags from Vlds[c][j]
    #pragma unroll
    for (int s = 0; s < 4; s++) {
      #pragma unroll
      for (int cb = 0; cb < 4; cb++) {
        s16x4 vb = *(const s16x4*)(Vlds + (cb * 16 + l15) * 72 + s * 16 + quad * 4);
        O[0][cb] = __builtin_amdgcn_mfma_f32_16x16x16bf16_1k(Pb[0][s], vb, O[0][cb], 0, 0, 0);
        O[1][cb] = __builtin_amdgcn_mfma_f32_16x16x16bf16_1k(Pb[1][s], vb, O[1][cb], 0, 0, 0);
      }
    }
#else
    __threadfence_block();
    #pragma unroll
    for (int ib = 0; ib < 2; ib++) {
      short8 pa0 = *(const short8*)&Plds[wave][(ib * 16 + l15) * 72 + quad * 8];
      short8 pa1 = *(const short8*)&Plds[wave][(ib * 16 + l15) * 72 + quad * 8 + 32];
      #pragma unroll
      for (int cb = 0; cb < 4; cb++) {
        const ushort* vbp = Vlds + (cb * 16 + l15) * 72 + quad * 8;
        short8 v0 = *(const short8*)vbp;
        short8 v1 = *(const short8*)(vbp + 32);
        O[ib][cb] = mfma16(pa0, v0, O[ib][cb]);
        O[ib][cb] = mfma16(pa1, v1, O[ib][cb]);
      }
    }
#endif
  }

  // epilogue: unnormalized O partials (bf16) + l partials
  size_t slice = (size_t)(bh * njs + js) * 4096;
  #pragma unroll
  for (int ib = 0; ib < 2; ib++) {
    float lv = lsum[ib];
    lv += __shfl_xor(lv, 16, 64);
    lv += __shfl_xor(lv, 32, 64);
    if (quad == 0) pl[slice + i0 + ib * 16 + l15] = lv;
    #pragma unroll
    for (int cb = 0; cb < 4; cb++)
      #pragma unroll
      for (int r = 0; r < 4; r++)
        po[(slice + i0 + ib * 16 + quad * 4 + r) * 64 + cb * 16 + l15] = f2b(O[ib][cb][r]);
  }
}

// ------------- kernel 5: partial reduce + normalize + SE-gated blend -------------
// grid (64 itile, 4 b, 2 chalf)
__global__ __launch_bounds__(256) void sc_combine(const float* __restrict__ x1, const float* __restrict__ x2,
                                                  const ushort* __restrict__ po, const float* __restrict__ pl,
                                                  const float* __restrict__ sey,
                                                  float* __restrict__ out, int jsbits) {
  int njs = 1 << jsbits;
  int itile = blockIdx.x, b = blockIdx.y, ch = blockIdx.z, t = threadIdx.x;
  __shared__ float hl[2][32 * 65];   // [head][c-local][p]
  #pragma unroll
  for (int head = 0; head < 2; head++) {
    int bh = b * 2 + head;
    int i = t >> 2, c8 = (t & 3) * 8;
    float sum[8];
    #pragma unroll
    for (int k = 0; k < 8; k++) sum[k] = 0.f;
    float lacc = 0.f;
    for (int js = 0; js < njs; js++) {
      size_t base = ((size_t)(bh * njs + js)) * 4096;
      uint4 u = *(const uint4*)(po + base * 64 + (size_t)(itile * 64 + i) * 64 + ch * 32 + c8);
      const ushort* us = (const ushort*)&u;
      #pragma unroll
      for (int k = 0; k < 8; k++) sum[k] += b2f(us[k]);
      lacc += pl[base + itile * 64 + i];
    }
    float inv = 1.f / lacc;
    #pragma unroll
    for (int k = 0; k < 8; k++) hl[head][(c8 + k) * 65 + i] = sum[k] * inv;
  }
  __syncthreads();
  #pragma unroll
  for (int it = 0; it < 8; it++) {
    int idx = it * 256 + t;
    int cl = idx >> 6, p = idx & 63;
    int c = ch * 32 + cl;
    size_t gi = ((size_t)(b * 64 + c)) * 4096 + itile * 64 + p;
    float xv = x1[gi] + x2[gi];
    float sig = 1.f / (1.f + fexp2(-xv * sey[b * 64 + c] * 1.44269504f));
    float h1 = hl[0][cl * 65 + p], h2 = hl[1][cl * 65 + p];
    out[gi] = 2.f * (h1 * sig + h2 * (1.f - sig));
  }
}

extern "C" void kernel_launch(void* const* d_in, const int* in_sizes, int n_in,
                              void* d_out, int out_size, void* d_ws, size_t ws_size,
                              hipStream_t stream) {
  (void)in_sizes; (void)n_in; (void)out_size;
  const float* x1    = (const float*)d_in[0];
  const float* x2    = (const float*)d_in[1];
  const float* se_w1 = (const float*)d_in[2];
  const float* se_w2 = (const float*)d_in[3];
  const float* gamma = (const float*)d_in[4];
  const float* beta  = (const float*)d_in[5];
  const float* wq    = (const float*)d_in[6];
  const float* bq    = (const float*)d_in[7];
  const float* wk    = (const float*)d_in[8];
  const float* bk    = (const float*)d_in[9];
  const float* wv    = (const float*)d_in[10];
  const float* bv    = (const float*)d_in[11];
  float* out = (float*)d_out;
  char* ws = (char*)d_ws;
  float*  stats = (float*)(ws + STATS_OFF);
  float*  ad    = (float*)(ws + AD_OFF);
  float*  sey   = (float*)(ws + SEY_OFF);
  float*  biasb = (float*)(ws + BIAS_OFF);
  ushort* wqb   = (ushort*)(ws + WQB_OFF);
  ushort* wkb   = (ushort*)(ws + WKB_OFF);
  ushort* wvb   = (ushort*)(ws + WVB_OFF);
  ushort* qb    = (ushort*)(ws + Q_OFF);
  ushort* kb    = (ushort*)(ws + K_OFF);
  ushort* vb    = (ushort*)(ws + V_OFF);

  // js split: largest of {8,4,2} whose partials fit the workspace (ws_size is fixed
  // per process, so this choice is identical on every call).
  int jsbits = 1;
  for (int jb = 3; jb >= 2; jb--) {
    size_t need = (size_t)PO_OFF + ((size_t)8 * 4096 * 64 * 2 + (size_t)8 * 4096 * 4) * (1u << jb);
    if (ws_size >= need) { jsbits = jb; break; }
  }
  int njs = 1 << jsbits;
  ushort* pob = (ushort*)(ws + PO_OFF);
  float*  plb = (float*)(ws + PO_OFF + (size_t)8 * njs * 4096 * 64 * 2);

  sc_stats  <<<1024, 256, 0, stream>>>(x1, x2, stats);
  sc_prep   <<<1, 256, 0, stream>>>(stats, se_w1, se_w2, gamma, beta,
                                    wq, bq, wk, bk, wv, bv,
                                    ad, sey, biasb, wqb, wkb, wvb);
  sc_proj   <<<dim3(64, 3, 4), 256, 0, stream>>>(x1, x2, ad, biasb,
                                                 wqb, wkb, wvb, qb, kb, vb);
  sc_flash  <<<8 * 32 * njs, 256, 0, stream>>>(qb, kb, vb, pob, plb, jsbits);
  sc_combine<<<dim3(64, 4, 2), 256, 0, stream>>>(x1, x2, pob, plb, sey, out, jsbits);
}

// Round 7
// 178.784 us; speedup vs baseline: 2.5300x; 2.5300x over previous
//
#include <hip/hip_runtime.h>

// B=4, C=64, H=W=64, N=4096, GROUPS=32 (2 ch/group), R=4.
// ws layout (bytes):
#define STATS_OFF 0                       // [1024][5] fp32 partial sums (bc*4+chunk)
#define AD_OFF    20480                   // [src(3)][b*64+c][2] fp32 (a, d)
#define SEY_OFF   26624                   // [b*64+c] fp32
#define BIAS_OFF  27648                   // fp32[1280]: [0:256) v(b,o); [256:768) q(bh,o); [768:1280) k(bh,o)
#define WQB_OFF   32768                   // bf16 wq*qscale [o][c] 8KB
#define WKB_OFF   40960                   // bf16 wk
#define WVB_OFF   49152                   // bf16 wv
#define Q_OFF     57344                   // [bh][n][c] bf16, 4MB (q pre-scaled)
#define K_OFF     (Q_OFF + 4194304)       // [bh][n][c] bf16, 4MB
#define V_OFF     (K_OFF + 4194304)       // [b][c][n]  bf16, 2MB
#define PO_OFF    (V_OFF + 2097152)       // [bh][js][n][c] bf16 partials, then pl fp32

#define QSCALE 0.18033688f                // 0.125 * log2(e)

typedef __attribute__((ext_vector_type(8))) short  short8;
typedef __attribute__((ext_vector_type(4))) short  s16x4;
typedef __attribute__((ext_vector_type(2))) unsigned int u32x2;
typedef __attribute__((ext_vector_type(4))) float  f32x4;

#if __has_builtin(__builtin_amdgcn_mfma_f32_16x16x16bf16_1k)
#define HAS_1K 1
#else
#define HAS_1K 0
#endif

#if __has_builtin(__builtin_amdgcn_exp2f)
__device__ inline float fexp2(float x) { return __builtin_amdgcn_exp2f(x); }  // raw v_exp_f32
#else
__device__ inline float fexp2(float x) { return exp2f(x); }
#endif

__device__ inline ushort f2b(float f) {   // round-half-up to bf16
  return (ushort)((__float_as_uint(f) + 0x8000u) >> 16);
}
__device__ inline unsigned pack2(float x, float y) {  // two bf16 in one dword
  unsigned ux = __float_as_uint(x) + 0x8000u;
  unsigned uy = __float_as_uint(y) + 0x8000u;
  return __builtin_amdgcn_perm(uy, ux, 0x07060302);
}
__device__ inline float b2f(ushort u) { return __uint_as_float(((unsigned)u) << 16); }

__device__ inline f32x4 mfma16(short8 a, short8 b, f32x4 c) {
  return __builtin_amdgcn_mfma_f32_16x16x32_bf16(a, b, c, 0, 0, 0);
}

__device__ inline float wsum64(float v) {
  #pragma unroll
  for (int o = 32; o > 0; o >>= 1) v += __shfl_down(v, o, 64);
  return v;
}

// ---------------- kernel 1: per-(b,c) partial sums, 4 spatial chunks -----------------
__global__ __launch_bounds__(256) void sc_stats(const float* __restrict__ x1,
                                                const float* __restrict__ x2,
                                                float* __restrict__ stats) {
  int blk = blockIdx.x;                 // 1024 = bc*4 + chunk
  int bc = blk >> 2, chunk = blk & 3;
  const float4* p1 = (const float4*)(x1 + (size_t)bc * 4096 + chunk * 1024);
  const float4* p2 = (const float4*)(x2 + (size_t)bc * 4096 + chunk * 1024);
  float4 a = p1[threadIdx.x], b = p2[threadIdx.x];
  float s1 = a.x + a.y + a.z + a.w;
  float q1 = a.x*a.x + a.y*a.y + a.z*a.z + a.w*a.w;
  float s2 = b.x + b.y + b.z + b.w;
  float q2 = b.x*b.x + b.y*b.y + b.z*b.z + b.w*b.w;
  float p12 = a.x*b.x + a.y*b.y + a.z*b.z + a.w*b.w;
  s1 = wsum64(s1); q1 = wsum64(q1); s2 = wsum64(s2); q2 = wsum64(q2); p12 = wsum64(p12);
  __shared__ float red[4][5];
  int w = threadIdx.x >> 6, ln = threadIdx.x & 63;
  if (ln == 0) { red[w][0] = s1; red[w][1] = q1; red[w][2] = s2; red[w][3] = q2; red[w][4] = p12; }
  __syncthreads();
  if (threadIdx.x < 5) {
    float acc = 0;
    #pragma unroll
    for (int ww = 0; ww < 4; ww++) acc += red[ww][threadIdx.x];
    stats[(size_t)blk * 5 + threadIdx.x] = acc;
  }
}

// ------------- kernel 2: SE MLP + GN fold + folded biases + bf16 weights -------------
__global__ __launch_bounds__(256) void sc_prep(const float* __restrict__ stats,
                                               const float* __restrict__ w1,
                                               const float* __restrict__ w2,
                                               const float* __restrict__ gamma,
                                               const float* __restrict__ beta,
                                               const float* __restrict__ wq, const float* __restrict__ bq,
                                               const float* __restrict__ wk, const float* __restrict__ bk,
                                               const float* __restrict__ wv, const float* __restrict__ bv,
                                               float* __restrict__ ad, float* __restrict__ sey,
                                               float* __restrict__ biasbuf,
                                               ushort* __restrict__ wqb, ushort* __restrict__ wkb,
                                               ushort* __restrict__ wvb) {
  int t = threadIdx.x; int b = t >> 6, c = t & 63;
  float s1 = 0, q1 = 0, s2 = 0, q2 = 0, p12 = 0;
  #pragma unroll
  for (int ch = 0; ch < 4; ch++) {
    const float* sp = stats + (size_t)(t * 4 + ch) * 5;
    s1 += sp[0]; q1 += sp[1]; s2 += sp[2]; q2 += sp[3]; p12 += sp[4];
  }
  float sx = s1 + s2, qx = q1 + q2 + 2.f * p12;
  __shared__ float smu[256], sS[3][256], sQ[3][256], sy[16], sdd[3][256];
  smu[t] = sx * (1.f / 4096.f);
  sS[0][t] = sx; sQ[0][t] = qx; sS[1][t] = s1; sQ[1][t] = q1; sS[2][t] = s2; sQ[2][t] = q2;
  __syncthreads();
  if (t < 16) {
    int bb = t >> 2, r = t & 3; float acc = 0.f;
    for (int cc = 0; cc < 64; cc++) acc += w1[r*64+cc] * smu[bb*64+cc];
    sy[t] = fmaxf(acc, 0.f);
  }
  __syncthreads();
  float acc = 0.f;
  #pragma unroll
  for (int r = 0; r < 4; r++) acc += w2[c*4+r] * sy[b*4+r];
  sey[t] = 1.f / (1.f + fexp2(-acc * 1.44269504f));
  int prt = t ^ 1;
  float g = gamma[c], bt = beta[c];
  #pragma unroll
  for (int s = 0; s < 3; s++) {
    float S = sS[s][t] + sS[s][prt], Q = sQ[s][t] + sQ[s][prt];
    float mean = S * (1.f / 8192.f);
    float var  = Q * (1.f / 8192.f) - mean * mean;
    float rstd = rsqrtf(var + 1e-6f);
    float a = g * rstd;
    float d = bt - mean * a;
    ad[((s*256) + t)*2 + 0] = a;
    ad[((s*256) + t)*2 + 1] = d;
    sdd[s][t] = d;
  }
  __syncthreads();
  // folded biases: bias' = W*d + bias (q scaled); 1280 of them
  #pragma unroll
  for (int k = 0; k < 5; k++) {
    int idx = k * 256 + t;
    const float* W; const float* bs; const float* dd; int o; float scale = 1.f;
    if (idx < 256)      { int bb = idx >> 6; o = idx & 63; W = wv; bs = bv; dd = &sdd[0][bb*64]; }
    else if (idx < 768) { int r = idx - 256; int bh = r >> 6; o = r & 63; W = wq; bs = bq;
                          dd = &sdd[1 + (bh & 1)][(bh >> 1)*64]; scale = QSCALE; }
    else                { int r = idx - 768; int bh = r >> 6; o = r & 63; W = wk; bs = bk;
                          dd = &sdd[1 + (bh & 1)][(bh >> 1)*64]; }
    float a2 = bs[o];
    for (int cc = 0; cc < 64; cc++) a2 += W[o*64+cc] * dd[cc];
    biasbuf[idx] = a2 * scale;
  }
  for (int i = t; i < 4096; i += 256) {
    wqb[i] = f2b(wq[i] * QSCALE);
    wkb[i] = f2b(wk[i]);
    wvb[i] = f2b(wv[i]);
  }
}

// ------------- kernel 3: GN + 1x1 conv projections via MFMA, LDS-staged stores -------------
__global__ __launch_bounds__(256) void sc_proj(const float* __restrict__ x1, const float* __restrict__ x2,
    const float* __restrict__ ad, const float* __restrict__ biasbuf,
    const ushort* __restrict__ wqb, const ushort* __restrict__ wkb, const ushort* __restrict__ wvb,
    ushort* __restrict__ qout, ushort* __restrict__ kout, ushort* __restrict__ vout) {
  int pt = blockIdx.x, src = blockIdx.y, b = blockIdx.z, t = threadIdx.x;
  __shared__ ushort xlds[64 * 66];   // xn tile [p][c], bf16
  __shared__ ushort olds[64 * 66];   // output assembly tile
  __shared__ float sbias[2][64];
  if (t < 128) {
    int proj = t >> 6, o = t & 63;
    float bb;
    if (src == 0) bb = (proj == 0) ? biasbuf[b*64 + o] : 0.f;
    else          bb = biasbuf[256 + (proj ? 512 : 0) + (b*2 + src - 1)*64 + o];
    sbias[proj][o] = bb;
  }
  {
    int c = t >> 2, pq = (t & 3) * 16;
    const float* px1 = x1 + ((size_t)(b*64 + c))*4096 + pt*64 + pq;
    const float* px2 = x2 + ((size_t)(b*64 + c))*4096 + pt*64 + pq;
    float av = ad[((src*256) + b*64 + c)*2 + 0];
    #pragma unroll
    for (int k4 = 0; k4 < 4; k4++) {
      float4 v1 = *(const float4*)(px1 + 4*k4);
      float xv[4];
      if (src == 1) { xv[0]=v1.x; xv[1]=v1.y; xv[2]=v1.z; xv[3]=v1.w; }
      else {
        float4 v2 = *(const float4*)(px2 + 4*k4);
        if (src == 2) { xv[0]=v2.x; xv[1]=v2.y; xv[2]=v2.z; xv[3]=v2.w; }
        else { xv[0]=v1.x+v2.x; xv[1]=v1.y+v2.y; xv[2]=v1.z+v2.z; xv[3]=v1.w+v2.w; }
      }
      #pragma unroll
      for (int k = 0; k < 4; k++)
        xlds[(pq + 4*k4 + k)*66 + c] = f2b(av * xv[k]);
    }
  }
  __syncthreads();
  int wave = t >> 6, lane = t & 63, quad = lane >> 4, l15 = lane & 15;
  int orow = t >> 2, ocol = (t & 3) * 16;   // coalesced write-out mapping
  if (src == 0) {
    // V[o][p]: A = Wv (m=o,k=c), B = xn (k=c,n=p). wave = o-sub.
    const ushort* ap = wvb + (wave*16 + l15)*64 + quad*8;
    short8 a0 = *(const short8*)ap;
    short8 a1 = *(const short8*)(ap + 32);
    f32x4 cinit;
    #pragma unroll
    for (int r = 0; r < 4; r++) cinit[r] = sbias[0][wave*16 + quad*4 + r];
    #pragma unroll
    for (int s = 0; s < 4; s++) {
      const ushort* bp = xlds + (s*16 + l15)*66 + quad*8;
      short8 b0 = *(const short8*)bp;
      short8 b1 = *(const short8*)(bp + 32);
      f32x4 acc = mfma16(a0, b0, cinit);
      acc = mfma16(a1, b1, acc);
      #pragma unroll
      for (int r = 0; r < 4; r++)
        olds[(wave*16 + quad*4 + r)*66 + s*16 + l15] = f2b(acc[r]);   // [o][p]
    }
    __syncthreads();
    uint4 w0 = *(const uint4*)&olds[orow*66 + ocol];
    uint4 w1 = *(const uint4*)&olds[orow*66 + ocol + 8];
    ushort* dst = vout + ((size_t)(b*64 + orow))*4096 + pt*64 + ocol;
    *(uint4*)dst = w0; *(uint4*)(dst + 8) = w1;
  } else {
    // Q/K[p][o]: A = xn (m=p,k=c), B = W (k=c,n=o). wave = p-sub.
    int bh = b*2 + (src - 1);
    const ushort* ap = xlds + (wave*16 + l15)*66 + quad*8;
    short8 a0 = *(const short8*)ap;
    short8 a1 = *(const short8*)(ap + 32);
    #pragma unroll
    for (int proj = 0; proj < 2; proj++) {
      const ushort* Wb = proj == 0 ? wqb : wkb;
      ushort* dst = proj == 0 ? qout : kout;
      #pragma unroll
      for (int s = 0; s < 4; s++) {
        const ushort* bp = Wb + (s*16 + l15)*64 + quad*8;
        short8 b0 = *(const short8*)bp;
        short8 b1 = *(const short8*)(bp + 32);
        float bb = sbias[proj][s*16 + l15];
        f32x4 acc = {bb, bb, bb, bb};
        acc = mfma16(a0, b0, acc);
        acc = mfma16(a1, b1, acc);
        #pragma unroll
        for (int r = 0; r < 4; r++)
          olds[(wave*16 + quad*4 + r)*66 + s*16 + l15] = f2b(acc[r]);  // [p][o]
      }
      __syncthreads();
      uint4 w0 = *(const uint4*)&olds[orow*66 + ocol];
      uint4 w1 = *(const uint4*)&olds[orow*66 + ocol + 8];
      ushort* dp = dst + ((size_t)bh*4096 + pt*64 + orow)*64 + ocol;
      *(uint4*)dp = w0; *(uint4*)(dp + 8) = w1;
      if (proj == 0) __syncthreads();   // olds reused by proj 1
    }
  }
}

// ------------- kernel 4: flash attention, S^T + _1k, K/V in LDS, reg prefetch -------------
// grid 8*32*njs: bh = blk&7 (XCD-local K/V), rest = blk>>3: js = rest&(njs-1), itile = rest>>jsbits.
// NOTE: min-waves arg stays 4 — (256,8) forces VGPR<=32 and catastrophic scratch spill
// (R6: 646MB FETCH, 380us). At 64 VGPR the HW can still co-resident 8 blocks/CU.
__global__ __launch_bounds__(256, 4) void sc_flash(const ushort* __restrict__ qg,
                                                   const ushort* __restrict__ kg,
                                                   const ushort* __restrict__ vg,
                                                   ushort* __restrict__ po,
                                                   float* __restrict__ pl,
                                                   int jsbits) {
  int blk = blockIdx.x;
  int bh = blk & 7, rest = blk >> 3;
  int njs = 1 << jsbits, njt = 64 >> jsbits;
  int js = rest & (njs - 1), itile = rest >> jsbits;
  int jbase = js * (njt << 6);
  int b = bh >> 1;
  int t = threadIdx.x, wave = t >> 6, lane = t & 63, quad = lane >> 4, l15 = lane & 15;
  int i0 = itile * 128 + wave * 32;

  __shared__ ushort Klds[64 * 72];       // [j][c]
  __shared__ ushort Vlds[64 * 72];       // [c][j]
#if !HAS_1K
  __shared__ ushort Plds[4][32 * 72];    // per-wave P [i][j] (fallback only)
#endif

  // Q B-frags (B[k=c][n=i]): lane -> i=l15, c=quad*8(+32); two i-blocks
  const ushort* qbase = qg + ((size_t)bh * 4096 + i0 + l15) * 64 + quad * 8;
  short8 Qb[2][2];
  Qb[0][0] = *(const short8*)qbase;
  Qb[0][1] = *(const short8*)(qbase + 32);
  Qb[1][0] = *(const short8*)(qbase + 16 * 64);
  Qb[1][1] = *(const short8*)(qbase + 16 * 64 + 32);

  f32x4 O[2][4]; const f32x4 zero4 = {0.f, 0.f, 0.f, 0.f};
  #pragma unroll
  for (int ib = 0; ib < 2; ib++)
    #pragma unroll
    for (int cb = 0; cb < 4; cb++) O[ib][cb] = zero4;
  float lsum[2] = {0.f, 0.f};

  // staging: thread -> row t>>2 (j for K, c for V), 32B chunk (t&3)*16
  int sr = t >> 2, sc = (t & 3) * 16;
  const ushort* ksrc = kg + ((size_t)bh * 4096 + jbase + sr) * 64 + sc;
  const ushort* vsrc = vg + ((size_t)(b * 64 + sr)) * 4096 + jbase + sc;
  ushort* kdst = Klds + sr * 72 + sc;
  ushort* vdst = Vlds + sr * 72 + sc;

  // register prefetch of tile 0
  uint4 kr0 = *(const uint4*)ksrc, kr1 = *(const uint4*)(ksrc + 8);
  uint4 vr0 = *(const uint4*)vsrc, vr1 = *(const uint4*)(vsrc + 8);
  ksrc += 4096; vsrc += 64;

  #pragma unroll 1
  for (int jt = 0; jt < njt; jt++) {
    __syncthreads();                     // prior iteration's LDS reads done
    *(uint4*)kdst = kr0; *(uint4*)(kdst + 8) = kr1;
    *(uint4*)vdst = vr0; *(uint4*)(vdst + 8) = vr1;
    __syncthreads();
    if (jt + 1 < njt) {                  // issue next tile's loads; land during compute
      kr0 = *(const uint4*)ksrc; kr1 = *(const uint4*)(ksrc + 8);
      vr0 = *(const uint4*)vsrc; vr1 = *(const uint4*)(vsrc + 8);
      ksrc += 4096; vsrc += 64;
    }

    // S^T = K Q^T : D[j=16s+quad*4+r][i=ib*16+l15]
    f32x4 S[2][4];
    #pragma unroll
    for (int s = 0; s < 4; s++) {
      const ushort* kp = Klds + (s * 16 + l15) * 72 + quad * 8;
      short8 ka0 = *(const short8*)kp;
      short8 ka1 = *(const short8*)(kp + 32);
      #pragma unroll
      for (int ib = 0; ib < 2; ib++) {
        f32x4 acc = mfma16(ka0, Qb[ib][0], zero4);
        S[ib][s] = mfma16(ka1, Qb[ib][1], acc);
      }
    }

    // P = exp2(S) (no-max softmax; scores bounded); per-lane l accumulation
#if HAS_1K
    s16x4 Pb[2][4];
#endif
    #pragma unroll
    for (int ib = 0; ib < 2; ib++) {
      #pragma unroll
      for (int s = 0; s < 4; s++) {
        float p0 = fexp2(S[ib][s][0]);
        float p1 = fexp2(S[ib][s][1]);
        float p2 = fexp2(S[ib][s][2]);
        float p3 = fexp2(S[ib][s][3]);
        lsum[ib] += (p0 + p1) + (p2 + p3);
#if HAS_1K
        u32x2 wpk = {pack2(p0, p1), pack2(p2, p3)};
        Pb[ib][s] = __builtin_bit_cast(s16x4, wpk);
#else
        ushort* pw = &Plds[wave][(ib * 16 + l15) * 72 + s * 16 + quad * 4];
        pw[0] = f2b(p0); pw[1] = f2b(p1); pw[2] = f2b(p2); pw[3] = f2b(p3);
#endif
      }
    }

#if HAS_1K
    // O += P V : 16x16x16_1k, A = P (S^T C-layout direct), B = V b64 frags from Vlds[c][j]
    #pragma unroll
    for (int s = 0; s < 4; s++) {
      #pragma unroll
      for (int cb = 0; cb < 4; cb++) {
        s16x4 vb = *(const s16x4*)(Vlds + (cb * 16 + l15) * 72 + s * 16 + quad * 4);
        O[0][cb] = __builtin_amdgcn_mfma_f32_16x16x16bf16_1k(Pb[0][s], vb, O[0][cb], 0, 0, 0);
        O[1][cb] = __builtin_amdgcn_mfma_f32_16x16x16bf16_1k(Pb[1][s], vb, O[1][cb], 0, 0, 0);
      }
    }
#else
    __threadfence_block();
    #pragma unroll
    for (int ib = 0; ib < 2; ib++) {
      short8 pa0 = *(const short8*)&Plds[wave][(ib * 16 + l15) * 72 + quad * 8];
      short8 pa1 = *(const short8*)&Plds[wave][(ib * 16 + l15) * 72 + quad * 8 + 32];
      #pragma unroll
      for (int cb = 0; cb < 4; cb++) {
        const ushort* vbp = Vlds + (cb * 16 + l15) * 72 + quad * 8;
        short8 v0 = *(const short8*)vbp;
        short8 v1 = *(const short8*)(vbp + 32);
        O[ib][cb] = mfma16(pa0, v0, O[ib][cb]);
        O[ib][cb] = mfma16(pa1, v1, O[ib][cb]);
      }
    }
#endif
  }

  // epilogue: unnormalized O partials (bf16) + l partials
  size_t slice = (size_t)(bh * njs + js) * 4096;
  #pragma unroll
  for (int ib = 0; ib < 2; ib++) {
    float lv = lsum[ib];
    lv += __shfl_xor(lv, 16, 64);
    lv += __shfl_xor(lv, 32, 64);
    if (quad == 0) pl[slice + i0 + ib * 16 + l15] = lv;
    #pragma unroll
    for (int cb = 0; cb < 4; cb++)
      #pragma unroll
      for (int r = 0; r < 4; r++)
        po[(slice + i0 + ib * 16 + quad * 4 + r) * 64 + cb * 16 + l15] = f2b(O[ib][cb][r]);
  }
}

// ------------- kernel 5: partial reduce + normalize + SE-gated blend -------------
// grid (64 itile, 4 b, 2 chalf)
__global__ __launch_bounds__(256) void sc_combine(const float* __restrict__ x1, const float* __restrict__ x2,
                                                  const ushort* __restrict__ po, const float* __restrict__ pl,
                                                  const float* __restrict__ sey,
                                                  float* __restrict__ out, int jsbits) {
  int njs = 1 << jsbits;
  int itile = blockIdx.x, b = blockIdx.y, ch = blockIdx.z, t = threadIdx.x;
  __shared__ float hl[2][32 * 65];   // [head][c-local][p]
  #pragma unroll
  for (int head = 0; head < 2; head++) {
    int bh = b * 2 + head;
    int i = t >> 2, c8 = (t & 3) * 8;
    float sum[8];
    #pragma unroll
    for (int k = 0; k < 8; k++) sum[k] = 0.f;
    float lacc = 0.f;
    for (int js = 0; js < njs; js++) {
      size_t base = ((size_t)(bh * njs + js)) * 4096;
      uint4 u = *(const uint4*)(po + base * 64 + (size_t)(itile * 64 + i) * 64 + ch * 32 + c8);
      const ushort* us = (const ushort*)&u;
      #pragma unroll
      for (int k = 0; k < 8; k++) sum[k] += b2f(us[k]);
      lacc += pl[base + itile * 64 + i];
    }
    float inv = 1.f / lacc;
    #pragma unroll
    for (int k = 0; k < 8; k++) hl[head][(c8 + k) * 65 + i] = sum[k] * inv;
  }
  __syncthreads();
  #pragma unroll
  for (int it = 0; it < 8; it++) {
    int idx = it * 256 + t;
    int cl = idx >> 6, p = idx & 63;
    int c = ch * 32 + cl;
    size_t gi = ((size_t)(b * 64 + c)) * 4096 + itile * 64 + p;
    float xv = x1[gi] + x2[gi];
    float sig = 1.f / (1.f + fexp2(-xv * sey[b * 64 + c] * 1.44269504f));
    float h1 = hl[0][cl * 65 + p], h2 = hl[1][cl * 65 + p];
    out[gi] = 2.f * (h1 * sig + h2 * (1.f - sig));
  }
}

extern "C" void kernel_launch(void* const* d_in, const int* in_sizes, int n_in,
                              void* d_out, int out_size, void* d_ws, size_t ws_size,
                              hipStream_t stream) {
  (void)in_sizes; (void)n_in; (void)out_size;
  const float* x1    = (const float*)d_in[0];
  const float* x2    = (const float*)d_in[1];
  const float* se_w1 = (const float*)d_in[2];
  const float* se_w2 = (const float*)d_in[3];
  const float* gamma = (const float*)d_in[4];
  const float* beta  = (const float*)d_in[5];
  const float* wq    = (const float*)d_in[6];
  const float* bq    = (const float*)d_in[7];
  const float* wk    = (const float*)d_in[8];
  const float* bk    = (const float*)d_in[9];
  const float* wv    = (const float*)d_in[10];
  const float* bv    = (const float*)d_in[11];
  float* out = (float*)d_out;
  char* ws = (char*)d_ws;
  float*  stats = (float*)(ws + STATS_OFF);
  float*  ad    = (float*)(ws + AD_OFF);
  float*  sey   = (float*)(ws + SEY_OFF);
  float*  biasb = (float*)(ws + BIAS_OFF);
  ushort* wqb   = (ushort*)(ws + WQB_OFF);
  ushort* wkb   = (ushort*)(ws + WKB_OFF);
  ushort* wvb   = (ushort*)(ws + WVB_OFF);
  ushort* qb    = (ushort*)(ws + Q_OFF);
  ushort* kb    = (ushort*)(ws + K_OFF);
  ushort* vb    = (ushort*)(ws + V_OFF);

  // js split: largest of {8,4,2} whose partials fit the workspace (ws_size is fixed
  // per process, so this choice is identical on every call).
  int jsbits = 1;
  for (int jb = 3; jb >= 2; jb--) {
    size_t need = (size_t)PO_OFF + ((size_t)8 * 4096 * 64 * 2 + (size_t)8 * 4096 * 4) * (1u << jb);
    if (ws_size >= need) { jsbits = jb; break; }
  }
  int njs = 1 << jsbits;
  ushort* pob = (ushort*)(ws + PO_OFF);
  float*  plb = (float*)(ws + PO_OFF + (size_t)8 * njs * 4096 * 64 * 2);

  sc_stats  <<<1024, 256, 0, stream>>>(x1, x2, stats);
  sc_prep   <<<1, 256, 0, stream>>>(stats, se_w1, se_w2, gamma, beta,
                                    wq, bq, wk, bk, wv, bv,
                                    ad, sey, biasb, wqb, wkb, wvb);
  sc_proj   <<<dim3(64, 3, 4), 256, 0, stream>>>(x1, x2, ad, biasb,
                                                 wqb, wkb, wvb, qb, kb, vb);
  sc_flash  <<<8 * 32 * njs, 256, 0, stream>>>(qb, kb, vb, pob, plb, jsbits);
  sc_combine<<<dim3(64, 4, 2), 256, 0, stream>>>(x1, x2, pob, plb, sey, out, jsbits);
}

// Round 8
// 151.686 us; speedup vs baseline: 2.9819x; 1.1786x over previous
//
#include <hip/hip_runtime.h>

// B=4, C=64, H=W=64, N=4096, GROUPS=32 (2 ch/group), R=4.
// ws layout (bytes):
#define STATS_OFF 0                       // [1024][5] fp32 partial sums (bc*4+chunk)
#define AD_OFF    20480                   // [src(3)][b*64+c][2] fp32 (a, d)
#define SEY_OFF   26624                   // [b*64+c] fp32
#define WQB_OFF   32768                   // bf16 wq*qscale [o][c] 8KB
#define WKB_OFF   40960                   // bf16 wk
#define WVB_OFF   49152                   // bf16 wv
#define Q_OFF     57344                   // [bh][n][c] bf16, 4MB (q pre-scaled)
#define K_OFF     (Q_OFF + 4194304)       // [bh][n][c] bf16, 4MB
#define V_OFF     (K_OFF + 4194304)       // [b][c][n]  bf16, 2MB
#define PO_OFF    (V_OFF + 2097152)       // [bh][js][n][c] bf16 partials, then pl fp32

#define QSCALE 0.18033688f                // 0.125 * log2(e)
// XOR swizzle (8-element granularity) -> balanced LDS bank phases for b128/b64 frag reads
#define SWZ(r) ((((r) & 7) << 3) ^ (((r) & 8) << 1))

typedef __attribute__((ext_vector_type(8))) short  short8;
typedef __attribute__((ext_vector_type(4))) short  s16x4;
typedef __attribute__((ext_vector_type(2))) unsigned int u32x2;
typedef __attribute__((ext_vector_type(4))) float  f32x4;

#if __has_builtin(__builtin_amdgcn_exp2f)
__device__ inline float fexp2(float x) { return __builtin_amdgcn_exp2f(x); }  // raw v_exp_f32
#else
__device__ inline float fexp2(float x) { return exp2f(x); }
#endif

__device__ inline ushort f2b(float f) {   // round-half-up to bf16
  return (ushort)((__float_as_uint(f) + 0x8000u) >> 16);
}
__device__ inline unsigned pack2(float x, float y) {  // bf16(x) | bf16(y)<<16
  unsigned ux = __float_as_uint(x) + 0x8000u;
  unsigned uy = __float_as_uint(y) + 0x8000u;
  return __builtin_amdgcn_perm(uy, ux, 0x07060302);
}
__device__ inline float b2f(ushort u) { return __uint_as_float(((unsigned)u) << 16); }

__device__ inline f32x4 mfma16(short8 a, short8 b, f32x4 c) {
  return __builtin_amdgcn_mfma_f32_16x16x32_bf16(a, b, c, 0, 0, 0);
}

__device__ inline float wsum64(float v) {
  #pragma unroll
  for (int o = 32; o > 0; o >>= 1) v += __shfl_down(v, o, 64);
  return v;
}

// ---------------- kernel 1: per-(b,c) partial sums + bf16 weight conversion -----------------
__global__ __launch_bounds__(256) void sc_stats(const float* __restrict__ x1,
                                                const float* __restrict__ x2,
                                                float* __restrict__ stats,
                                                const float* __restrict__ wq,
                                                const float* __restrict__ wk,
                                                const float* __restrict__ wv,
                                                ushort* __restrict__ wqb,
                                                ushort* __restrict__ wkb,
                                                ushort* __restrict__ wvb) {
  int blk = blockIdx.x;                 // 1024 = bc*4 + chunk
  int bc = blk >> 2, chunk = blk & 3;
  const float4* p1 = (const float4*)(x1 + (size_t)bc * 4096 + chunk * 1024);
  const float4* p2 = (const float4*)(x2 + (size_t)bc * 4096 + chunk * 1024);
  float4 a = p1[threadIdx.x], b = p2[threadIdx.x];
  float s1 = a.x + a.y + a.z + a.w;
  float q1 = a.x*a.x + a.y*a.y + a.z*a.z + a.w*a.w;
  float s2 = b.x + b.y + b.z + b.w;
  float q2 = b.x*b.x + b.y*b.y + b.z*b.z + b.w*b.w;
  float p12 = a.x*b.x + a.y*b.y + a.z*b.z + a.w*b.w;
  s1 = wsum64(s1); q1 = wsum64(q1); s2 = wsum64(s2); q2 = wsum64(q2); p12 = wsum64(p12);
  __shared__ float red[4][5];
  int w = threadIdx.x >> 6, ln = threadIdx.x & 63;
  if (ln == 0) { red[w][0] = s1; red[w][1] = q1; red[w][2] = s2; red[w][3] = q2; red[w][4] = p12; }
  __syncthreads();
  if (threadIdx.x < 5) {
    float acc = 0;
    #pragma unroll
    for (int ww = 0; ww < 4; ww++) acc += red[ww][threadIdx.x];
    stats[(size_t)blk * 5 + threadIdx.x] = acc;
  }
  // parallel bf16 weight conversion on the last 48 blocks (independent of stats)
  if (blk >= 976) {
    int idx = (blk - 976) * 256 + threadIdx.x;
    int arr = idx >> 12, e = idx & 4095;
    if (arr == 0)      wqb[e] = f2b(wq[e] * QSCALE);
    else if (arr == 1) wkb[e] = f2b(wk[e]);
    else               wvb[e] = f2b(wv[e]);
  }
}

// ------------- kernel 2: stats reduce + SE MLP + GN fold (small, 1 block) -------------
__global__ __launch_bounds__(256) void sc_prep(const float* __restrict__ stats,
                                               const float* __restrict__ w1,
                                               const float* __restrict__ w2,
                                               const float* __restrict__ gamma,
                                               const float* __restrict__ beta,
                                               float* __restrict__ ad, float* __restrict__ sey) {
  int t = threadIdx.x; int b = t >> 6, c = t & 63;
  float s1 = 0, q1 = 0, s2 = 0, q2 = 0, p12 = 0;
  #pragma unroll
  for (int ch = 0; ch < 4; ch++) {
    const float* sp = stats + (size_t)(t * 4 + ch) * 5;
    s1 += sp[0]; q1 += sp[1]; s2 += sp[2]; q2 += sp[3]; p12 += sp[4];
  }
  float sx = s1 + s2, qx = q1 + q2 + 2.f * p12;
  __shared__ float smu[256], sS[3][256], sQ[3][256], sy[16];
  smu[t] = sx * (1.f / 4096.f);
  sS[0][t] = sx; sQ[0][t] = qx; sS[1][t] = s1; sQ[1][t] = q1; sS[2][t] = s2; sQ[2][t] = q2;
  __syncthreads();
  if (t < 16) {
    int bb = t >> 2, r = t & 3; float acc = 0.f;
    for (int cc = 0; cc < 64; cc++) acc += w1[r*64+cc] * smu[bb*64+cc];
    sy[t] = fmaxf(acc, 0.f);
  }
  __syncthreads();
  float acc = 0.f;
  #pragma unroll
  for (int r = 0; r < 4; r++) acc += w2[c*4+r] * sy[b*4+r];
  sey[t] = 1.f / (1.f + fexp2(-acc * 1.44269504f));
  int prt = t ^ 1;
  float g = gamma[c], bt = beta[c];
  #pragma unroll
  for (int s = 0; s < 3; s++) {
    float S = sS[s][t] + sS[s][prt], Q = sQ[s][t] + sQ[s][prt];
    float mean = S * (1.f / 8192.f);
    float var  = Q * (1.f / 8192.f) - mean * mean;
    float rstd = rsqrtf(var + 1e-6f);
    float a = g * rstd;
    ad[((s*256) + t)*2 + 0] = a;
    ad[((s*256) + t)*2 + 1] = bt - mean * a;
  }
}

// ------------- kernel 3: GN + 1x1 conv projections via MFMA, parallel bias fold -------------
__global__ __launch_bounds__(256) void sc_proj(const float* __restrict__ x1, const float* __restrict__ x2,
    const float* __restrict__ ad,
    const float* __restrict__ wq, const float* __restrict__ bq,
    const float* __restrict__ wk, const float* __restrict__ bk,
    const float* __restrict__ wv, const float* __restrict__ bv,
    const ushort* __restrict__ wqb, const ushort* __restrict__ wkb, const ushort* __restrict__ wvb,
    ushort* __restrict__ qout, ushort* __restrict__ kout, ushort* __restrict__ vout) {
  int pt = blockIdx.x, src = blockIdx.y, b = blockIdx.z, t = threadIdx.x;
  __shared__ ushort xlds[64 * 66];   // xn tile [p][c], bf16
  __shared__ ushort olds[64 * 66];   // output assembly tile
  __shared__ float sd[64], sbias[2][64];
  if (t < 64) sd[t] = ad[((src*256) + b*64 + t)*2 + 1];
  __syncthreads();
  {
    int c = t >> 2, pq = (t & 3) * 16;
    const float* px1 = x1 + ((size_t)(b*64 + c))*4096 + pt*64 + pq;
    const float* px2 = x2 + ((size_t)(b*64 + c))*4096 + pt*64 + pq;
    float av = ad[((src*256) + b*64 + c)*2 + 0];
    #pragma unroll
    for (int k4 = 0; k4 < 4; k4++) {
      float4 v1 = *(const float4*)(px1 + 4*k4);
      float xv[4];
      if (src == 1) { xv[0]=v1.x; xv[1]=v1.y; xv[2]=v1.z; xv[3]=v1.w; }
      else {
        float4 v2 = *(const float4*)(px2 + 4*k4);
        if (src == 2) { xv[0]=v2.x; xv[1]=v2.y; xv[2]=v2.z; xv[3]=v2.w; }
        else { xv[0]=v1.x+v2.x; xv[1]=v1.y+v2.y; xv[2]=v1.z+v2.z; xv[3]=v1.w+v2.w; }
      }
      #pragma unroll
      for (int k = 0; k < 4; k++)
        xlds[(pq + 4*k4 + k)*66 + c] = f2b(av * xv[k]);
    }
  }
  int nbias = (src == 0) ? 64 : 128;
  if (t < nbias) {                   // bias' = W*d + bias (parallel across all 768 blocks)
    int proj = t >> 6, o = t & 63;
    const float* W  = (src == 0) ? wv : (proj == 0 ? wq : wk);
    const float* bs = (src == 0) ? bv : (proj == 0 ? bq : bk);
    float acc = bs[o];
    for (int cc = 0; cc < 64; cc++) acc += W[o*64+cc] * sd[cc];
    if (src != 0 && proj == 0) acc *= QSCALE;
    sbias[proj][o] = acc;
  }
  __syncthreads();
  int wave = t >> 6, lane = t & 63, quad = lane >> 4, l15 = lane & 15;
  int orow = t >> 2, ocol = (t & 3) * 16;   // coalesced write-out mapping
  if (src == 0) {
    // V[o][p]: A = Wv (m=o,k=c), B = xn (k=c,n=p). wave = o-sub.
    const ushort* ap = wvb + (wave*16 + l15)*64 + quad*8;
    short8 a0 = *(const short8*)ap;
    short8 a1 = *(const short8*)(ap + 32);
    f32x4 cinit;
    #pragma unroll
    for (int r = 0; r < 4; r++) cinit[r] = sbias[0][wave*16 + quad*4 + r];
    #pragma unroll
    for (int s = 0; s < 4; s++) {
      const ushort* bp = xlds + (s*16 + l15)*66 + quad*8;
      short8 b0 = *(const short8*)bp;
      short8 b1 = *(const short8*)(bp + 32);
      f32x4 acc = mfma16(a0, b0, cinit);
      acc = mfma16(a1, b1, acc);
      #pragma unroll
      for (int r = 0; r < 4; r++)
        olds[(wave*16 + quad*4 + r)*66 + s*16 + l15] = f2b(acc[r]);   // [o][p]
    }
    __syncthreads();
    uint4 w0 = *(const uint4*)&olds[orow*66 + ocol];
    uint4 w1 = *(const uint4*)&olds[orow*66 + ocol + 8];
    ushort* dst = vout + ((size_t)(b*64 + orow))*4096 + pt*64 + ocol;
    *(uint4*)dst = w0; *(uint4*)(dst + 8) = w1;
  } else {
    // Q/K[p][o]: A = xn (m=p,k=c), B = W (k=c,n=o). wave = p-sub.
    int bh = b*2 + (src - 1);
    const ushort* ap = xlds + (wave*16 + l15)*66 + quad*8;
    short8 a0 = *(const short8*)ap;
    short8 a1 = *(const short8*)(ap + 32);
    #pragma unroll
    for (int proj = 0; proj < 2; proj++) {
      const ushort* Wb = proj == 0 ? wqb : wkb;
      ushort* dst = proj == 0 ? qout : kout;
      #pragma unroll
      for (int s = 0; s < 4; s++) {
        const ushort* bp = Wb + (s*16 + l15)*64 + quad*8;
        short8 b0 = *(const short8*)bp;
        short8 b1 = *(const short8*)(bp + 32);
        float bb = sbias[proj][s*16 + l15];
        f32x4 acc = {bb, bb, bb, bb};
        acc = mfma16(a0, b0, acc);
        acc = mfma16(a1, b1, acc);
        #pragma unroll
        for (int r = 0; r < 4; r++)
          olds[(wave*16 + quad*4 + r)*66 + s*16 + l15] = f2b(acc[r]);  // [p][o]
      }
      __syncthreads();
      uint4 w0 = *(const uint4*)&olds[orow*66 + ocol];
      uint4 w1 = *(const uint4*)&olds[orow*66 + ocol + 8];
      ushort* dp = dst + ((size_t)bh*4096 + pt*64 + orow)*64 + ocol;
      *(uint4*)dp = w0; *(uint4*)(dp + 8) = w1;
      if (proj == 0) __syncthreads();   // olds reused by proj 1
    }
  }
}

// ------------- kernel 4: flash attention, i=64/wave, XOR-swizzled LDS, S^T + _1k -------------
// grid 8*16*njs: bh = blk&7 (XCD-local K/V), rest = blk>>3: js = rest&(njs-1), itile = rest>>jsbits.
// launch_bounds(256,2): VGPR budget 256 — needs ~170, must NOT spill (R6 lesson).
__global__ __launch_bounds__(256, 2) void sc_flash(const ushort* __restrict__ qg,
                                                   const ushort* __restrict__ kg,
                                                   const ushort* __restrict__ vg,
                                                   ushort* __restrict__ po,
                                                   float* __restrict__ pl,
                                                   int jsbits) {
  int blk = blockIdx.x;
  int bh = blk & 7, rest = blk >> 3;
  int njs = 1 << jsbits, njt = 64 >> jsbits;
  int js = rest & (njs - 1), itile = rest >> jsbits;   // itile 0..15
  int jbase = js * (njt << 6);
  int b = bh >> 1;
  int t = threadIdx.x, wave = t >> 6, lane = t & 63, quad = lane >> 4, l15 = lane & 15;
  int i0 = itile * 256 + wave * 64;

  __shared__ ushort Klds[64 * 64];       // [j][c^swz(j)]
  __shared__ ushort Vlds[64 * 64];       // [c][j^swz(c)]

  // Q B-frags (B[k=c][n=i]): lane -> i=l15, c=quad*8(+32); four i-blocks of 16
  short8 Qb[4][2];
  #pragma unroll
  for (int ib = 0; ib < 4; ib++) {
    const ushort* qp = qg + ((size_t)bh * 4096 + i0 + ib * 16 + l15) * 64 + quad * 8;
    Qb[ib][0] = *(const short8*)qp;
    Qb[ib][1] = *(const short8*)(qp + 32);
  }

  f32x4 O[4][4]; const f32x4 zero4 = {0.f, 0.f, 0.f, 0.f};
  #pragma unroll
  for (int ib = 0; ib < 4; ib++)
    #pragma unroll
    for (int cb = 0; cb < 4; cb++) O[ib][cb] = zero4;
  float lsum[4] = {0.f, 0.f, 0.f, 0.f};

  // staging: thread -> row t>>2 (j for K, c for V), 32B chunk (t&3)*16, swizzled dest
  int sr = t >> 2, sc = (t & 3) * 16;
  int swzs = SWZ(sr);
  int swzl = SWZ(l15);
  const ushort* ksrc = kg + ((size_t)bh * 4096 + jbase + sr) * 64 + sc;
  const ushort* vsrc = vg + ((size_t)(b * 64 + sr)) * 4096 + jbase + sc;
  ushort* kd0 = Klds + sr * 64 + (sc ^ swzs);
  ushort* kd1 = Klds + sr * 64 + ((sc + 8) ^ swzs);
  ushort* vd0 = Vlds + sr * 64 + (sc ^ swzs);
  ushort* vd1 = Vlds + sr * 64 + ((sc + 8) ^ swzs);

  // register prefetch of tile 0
  uint4 kr0 = *(const uint4*)ksrc, kr1 = *(const uint4*)(ksrc + 8);
  uint4 vr0 = *(const uint4*)vsrc, vr1 = *(const uint4*)(vsrc + 8);
  ksrc += 4096; vsrc += 64;

  #pragma unroll 1
  for (int jt = 0; jt < njt; jt++) {
    __syncthreads();                     // prior iteration's LDS reads done
    *(uint4*)kd0 = kr0; *(uint4*)kd1 = kr1;
    *(uint4*)vd0 = vr0; *(uint4*)vd1 = vr1;
    __syncthreads();
    if (jt + 1 < njt) {                  // issue next tile's loads; land during compute
      kr0 = *(const uint4*)ksrc; kr1 = *(const uint4*)(ksrc + 8);
      vr0 = *(const uint4*)vsrc; vr1 = *(const uint4*)(vsrc + 8);
      ksrc += 4096; vsrc += 64;
    }

    #pragma unroll
    for (int s = 0; s < 4; s++) {
      // S^T = K Q^T : D[j = s*16+quad*4+r][i = ib*16+l15]
      int rowK = (s * 16 + l15) * 64;
      short8 ka0 = *(const short8*)&Klds[rowK + ((quad * 8) ^ swzl)];
      short8 ka1 = *(const short8*)&Klds[rowK + ((quad * 8 + 32) ^ swzl)];
      f32x4 S[4];
      #pragma unroll
      for (int ib = 0; ib < 4; ib++) {
        f32x4 acc = mfma16(ka0, Qb[ib][0], zero4);
        S[ib] = mfma16(ka1, Qb[ib][1], acc);
      }
      // V B-frags: B[k = quad*4+idx][n -> c = cb*16+l15]
      s16x4 vbf[4];
      #pragma unroll
      for (int cb = 0; cb < 4; cb++)
        vbf[cb] = *(const s16x4*)&Vlds[(cb * 16 + l15) * 64 + ((s * 16 + quad * 4) ^ swzl)];
      // P = exp2(S); accumulate l; O += P V via 16x16x16_1k (A = P in-register)
      #pragma unroll
      for (int ib = 0; ib < 4; ib++) {
        float p0 = fexp2(S[ib][0]);
        float p1 = fexp2(S[ib][1]);
        float p2 = fexp2(S[ib][2]);
        float p3 = fexp2(S[ib][3]);
        lsum[ib] += (p0 + p1) + (p2 + p3);
        u32x2 wpk = {pack2(p0, p1), pack2(p2, p3)};
        s16x4 Pb = __builtin_bit_cast(s16x4, wpk);
        #pragma unroll
        for (int cb = 0; cb < 4; cb++)
          O[ib][cb] = __builtin_amdgcn_mfma_f32_16x16x16bf16_1k(Pb, vbf[cb], O[ib][cb], 0, 0, 0);
      }
    }
  }

  // epilogue: unnormalized O partials (bf16) + l partials
  // O[ib][cb][r]: i = i0 + ib*16 + quad*4 + r, c = cb*16 + l15
  size_t slice = (size_t)(bh * njs + js) * 4096;
  #pragma unroll
  for (int ib = 0; ib < 4; ib++) {
    float lv = lsum[ib];
    lv += __shfl_xor(lv, 16, 64);
    lv += __shfl_xor(lv, 32, 64);
    if (quad == 0) pl[slice + i0 + ib * 16 + l15] = lv;
    #pragma unroll
    for (int cb = 0; cb < 4; cb++)
      #pragma unroll
      for (int r = 0; r < 4; r++)
        po[(slice + i0 + ib * 16 + quad * 4 + r) * 64 + cb * 16 + l15] = f2b(O[ib][cb][r]);
  }
}

// ------------- kernel 5: partial reduce + normalize + SE-gated blend -------------
// grid (64 itile, 4 b, 2 chalf)
__global__ __launch_bounds__(256) void sc_combine(const float* __restrict__ x1, const float* __restrict__ x2,
                                                  const ushort* __restrict__ po, const float* __restrict__ pl,
                                                  const float* __restrict__ sey,
                                                  float* __restrict__ out, int jsbits) {
  int njs = 1 << jsbits;
  int itile = blockIdx.x, b = blockIdx.y, ch = blockIdx.z, t = threadIdx.x;
  __shared__ float hl[2][32 * 65];   // [head][c-local][p]
  #pragma unroll
  for (int head = 0; head < 2; head++) {
    int bh = b * 2 + head;
    int i = t >> 2, c8 = (t & 3) * 8;
    float sum[8];
    #pragma unroll
    for (int k = 0; k < 8; k++) sum[k] = 0.f;
    float lacc = 0.f;
    for (int js = 0; js < njs; js++) {
      size_t base = ((size_t)(bh * njs + js)) * 4096;
      uint4 u = *(const uint4*)(po + base * 64 + (size_t)(itile * 64 + i) * 64 + ch * 32 + c8);
      const ushort* us = (const ushort*)&u;
      #pragma unroll
      for (int k = 0; k < 8; k++) sum[k] += b2f(us[k]);
      lacc += pl[base + itile * 64 + i];
    }
    float inv = 1.f / lacc;
    #pragma unroll
    for (int k = 0; k < 8; k++) hl[head][(c8 + k) * 65 + i] = sum[k] * inv;
  }
  __syncthreads();
  #pragma unroll
  for (int it = 0; it < 8; it++) {
    int idx = it * 256 + t;
    int cl = idx >> 6, p = idx & 63;
    int c = ch * 32 + cl;
    size_t gi = ((size_t)(b * 64 + c)) * 4096 + itile * 64 + p;
    float xv = x1[gi] + x2[gi];
    float sig = 1.f / (1.f + fexp2(-xv * sey[b * 64 + c] * 1.44269504f));
    float h1 = hl[0][cl * 65 + p], h2 = hl[1][cl * 65 + p];
    out[gi] = 2.f * (h1 * sig + h2 * (1.f - sig));
  }
}

extern "C" void kernel_launch(void* const* d_in, const int* in_sizes, int n_in,
                              void* d_out, int out_size, void* d_ws, size_t ws_size,
                              hipStream_t stream) {
  (void)in_sizes; (void)n_in; (void)out_size;
  const float* x1    = (const float*)d_in[0];
  const float* x2    = (const float*)d_in[1];
  const float* se_w1 = (const float*)d_in[2];
  const float* se_w2 = (const float*)d_in[3];
  const float* gamma = (const float*)d_in[4];
  const float* beta  = (const float*)d_in[5];
  const float* wq    = (const float*)d_in[6];
  const float* bq    = (const float*)d_in[7];
  const float* wk    = (const float*)d_in[8];
  const float* bk    = (const float*)d_in[9];
  const float* wv    = (const float*)d_in[10];
  const float* bv    = (const float*)d_in[11];
  float* out = (float*)d_out;
  char* ws = (char*)d_ws;
  float*  stats = (float*)(ws + STATS_OFF);
  float*  ad    = (float*)(ws + AD_OFF);
  float*  sey   = (float*)(ws + SEY_OFF);
  ushort* wqb   = (ushort*)(ws + WQB_OFF);
  ushort* wkb   = (ushort*)(ws + WKB_OFF);
  ushort* wvb   = (ushort*)(ws + WVB_OFF);
  ushort* qb    = (ushort*)(ws + Q_OFF);
  ushort* kb    = (ushort*)(ws + K_OFF);
  ushort* vb    = (ushort*)(ws + V_OFF);

  // js split: largest of {8,4,2} whose partials fit the workspace (ws_size fixed per process).
  int jsbits = 1;
  for (int jb = 3; jb >= 2; jb--) {
    size_t need = (size_t)PO_OFF + ((size_t)8 * 4096 * 64 * 2 + (size_t)8 * 4096 * 4) * (1u << jb);
    if (ws_size >= need) { jsbits = jb; break; }
  }
  int njs = 1 << jsbits;
  ushort* pob = (ushort*)(ws + PO_OFF);
  float*  plb = (float*)(ws + PO_OFF + (size_t)8 * njs * 4096 * 64 * 2);

  sc_stats  <<<1024, 256, 0, stream>>>(x1, x2, stats, wq, wk, wv, wqb, wkb, wvb);
  sc_prep   <<<1, 256, 0, stream>>>(stats, se_w1, se_w2, gamma, beta, ad, sey);
  sc_proj   <<<dim3(64, 3, 4), 256, 0, stream>>>(x1, x2, ad,
                                                 wq, bq, wk, bk, wv, bv,
                                                 wqb, wkb, wvb, qb, kb, vb);
  sc_flash  <<<8 * 16 * njs, 256, 0, stream>>>(qb, kb, vb, pob, plb, jsbits);
  sc_combine<<<dim3(64, 4, 2), 256, 0, stream>>>(x1, x2, pob, plb, sey, out, jsbits);
}